// Round 3
// baseline (312.639 us; speedup 1.0000x reference)
//
#include <hip/hip_runtime.h>
#include <math.h>

#define NDIM 128
#define NHID 512
#define NEXPERT 64
#define NTOK 1024
#define TB 16  // tokens per expert batch

__device__ __forceinline__ float gelu_f(float v) {
    return 0.5f * v * (1.0f + erff(v * 0.7071067811865476f));
}

// K1: h1 = gelu(x @ gw1 + gb1)  grid (128 token-tiles, 2 f-halves)
__global__ __launch_bounds__(256) void gate1_kernel(
        const float* __restrict__ x, const float* __restrict__ gw1,
        const float* __restrict__ gb1, float* __restrict__ h1) {
    __shared__ float xs[8 * NDIM];
    const int j = threadIdx.x;
    const int t0 = blockIdx.x * 8;
    const int f = blockIdx.y * 256 + j;
    for (int i = j; i < 8 * NDIM / 4; i += 256)
        ((float4*)xs)[i] = ((const float4*)(x + t0 * NDIM))[i];
    __syncthreads();
    float acc[8];
#pragma unroll
    for (int t = 0; t < 8; ++t) acc[t] = 0.f;
    for (int k = 0; k < NDIM; ++k) {
        float w = gw1[k * NHID + f];
#pragma unroll
        for (int t = 0; t < 8; ++t) acc[t] += xs[t * NDIM + k] * w;
    }
    const float b = gb1[f];
#pragma unroll
    for (int t = 0; t < 8; ++t)
        h1[(t0 + t) * NHID + f] = gelu_f(acc[t] + b);
}

// K2: h2 = gelu(h1 @ gw2 + gb2)  grid (128 token-tiles, 4 f-chunks of 128)
__global__ __launch_bounds__(256) void gate2_kernel(
        const float* __restrict__ h1, const float* __restrict__ gw2,
        const float* __restrict__ gb2, float* __restrict__ h2) {
    __shared__ float hs[8 * NHID];
    const int j = threadIdx.x;
    const int t0 = blockIdx.x * 8;
    const int fl = j & 127;
    const int tg = j >> 7;          // 0..1 -> 4 tokens each
    const int f = blockIdx.y * 128 + fl;
    for (int i = j; i < 8 * NHID / 4; i += 256)
        ((float4*)hs)[i] = ((const float4*)(h1 + t0 * NHID))[i];
    __syncthreads();
    float acc[4] = {0.f, 0.f, 0.f, 0.f};
    for (int k = 0; k < NHID; ++k) {
        float w = gw2[k * NHID + f];
#pragma unroll
        for (int t = 0; t < 4; ++t)
            acc[t] += hs[(tg * 4 + t) * NHID + k] * w;
    }
    const float b = gb2[f];
#pragma unroll
    for (int t = 0; t < 4; ++t)
        h2[(t0 + tg * 4 + t) * NHID + f] = gelu_f(acc[t] + b);
}

// K3: sigmoid gate + top-2 + normalize. grid 128 (8-token tiles); lane=expert.
__global__ __launch_bounds__(256) void gate3_top2_kernel(
        const float* __restrict__ h2, const float* __restrict__ gw3,
        const float* __restrict__ gb3, int* __restrict__ eidx,
        float* __restrict__ wval) {
    __shared__ float hs[8 * NHID];
    const int j = threadIdx.x;
    const int t0 = blockIdx.x * 8;
    for (int i = j; i < 8 * NHID / 4; i += 256)
        ((float4*)hs)[i] = ((const float4*)(h2 + t0 * NHID))[i];
    __syncthreads();
    const int w = j >> 6;     // wave 0..3 -> 2 tokens each
    const int lane = j & 63;  // expert index
    float acc[2] = {0.f, 0.f};
    for (int k = 0; k < NHID; ++k) {
        float g = gw3[k * NEXPERT + lane];
#pragma unroll
        for (int i = 0; i < 2; ++i) acc[i] += hs[(w * 2 + i) * NHID + k] * g;
    }
    const float bias = gb3[lane];
#pragma unroll
    for (int i = 0; i < 2; ++i) {
        const int t = t0 + w * 2 + i;
        float s = 1.f / (1.f + expf(-(acc[i] + bias)));
        float v = s; int ix = lane;
#pragma unroll
        for (int off = 32; off >= 1; off >>= 1) {
            float ov = __shfl_xor(v, off);
            int oi = __shfl_xor(ix, off);
            if (ov > v || (ov == v && oi < ix)) { v = ov; ix = oi; }
        }
        const float v0 = v; const int i0 = ix;
        float v2 = (lane == i0) ? -1.f : s; int ix2 = lane;
#pragma unroll
        for (int off = 32; off >= 1; off >>= 1) {
            float ov = __shfl_xor(v2, off);
            int oi = __shfl_xor(ix2, off);
            if (ov > v2 || (ov == v2 && oi < ix2)) { v2 = ov; ix2 = oi; }
        }
        if (lane == 0) {
            float inv = 1.f / (v0 + v2);
            eidx[t * 2] = i0;  eidx[t * 2 + 1] = ix2;
            wval[t * 2] = v0 * inv;  wval[t * 2 + 1] = v2 * inv;
        }
    }
}

// K3b: deterministic per-expert lists via block scan (index order).
__global__ __launch_bounds__(256) void build_lists_kernel(
        const int* __restrict__ eidx, int* __restrict__ elist,
        int* __restrict__ ecnt) {
    const int e = blockIdx.x;
    const int j = threadIdx.x;
    __shared__ int cnts[256];
    int my[8];
    int mc = 0;
#pragma unroll
    for (int q = 0; q < 8; ++q) {
        int i = j * 8 + q;
        if (eidx[i] == e) my[mc++] = i;
    }
    cnts[j] = mc;
    __syncthreads();
    for (int off = 1; off < 256; off <<= 1) {
        int other = (j >= off) ? cnts[j - off] : 0;
        __syncthreads();
        cnts[j] += other;
        __syncthreads();
    }
    const int base = cnts[j] - mc;
    for (int q = 0; q < mc; ++q) elist[e * (NTOK * 2) + base + q] = my[q];
    if (j == 255) ecnt[e] = cnts[255];
}

// K4a: expert layer1. grid (64 e, 8 f-chunks of 64, 2 batch-strides).
// Thread: one f row (lane), wave = one token group of 4. tbuf[pair][f].
__global__ __launch_bounds__(256) void expert_l1_kernel(
        const float* __restrict__ x, const float* __restrict__ W1,
        const float* __restrict__ B1, const int* __restrict__ elist,
        const int* __restrict__ ecnt, float* __restrict__ tbuf) {
    const int e = blockIdx.x;
    const int f0 = blockIdx.y * 64;
    const int mb = blockIdx.z;
    const int n = ecnt[e];
    const int j = threadIdx.x;
    const int fl = j & 63;
    const int tg = j >> 6;  // 0..3, 4 tokens each
    const float* W1r = W1 + ((size_t)e * NHID + f0 + fl) * NDIM;
    const float b = B1[e * NHID + f0 + fl];
    const int* le = elist + e * (NTOK * 2);
    __shared__ float xs[TB * NDIM];
    __shared__ int prs[TB];
    for (int bt = mb; bt * TB < n; bt += 2) {
        const int nb = min(TB, n - bt * TB);
        __syncthreads();
        if (j < TB) prs[j] = (j < nb) ? le[bt * TB + j] : -1;
        __syncthreads();
        for (int i = j; i < nb * (NDIM / 4); i += 256)
            ((float4*)xs)[i] =
                ((const float4*)x)[(prs[i >> 5] >> 1) * (NDIM / 4) + (i & 31)];
        __syncthreads();
        float acc[4] = {0.f, 0.f, 0.f, 0.f};
        for (int k = 0; k < NDIM; k += 4) {
            float4 w = *(const float4*)(W1r + k);
#pragma unroll
            for (int t = 0; t < 4; ++t) {
                const float* xr = xs + (tg * 4 + t) * NDIM + k;
                acc[t] += w.x * xr[0] + w.y * xr[1] + w.z * xr[2] + w.w * xr[3];
            }
        }
#pragma unroll
        for (int t = 0; t < 4; ++t) {
            const int tt = tg * 4 + t;
            const int pr = prs[tt];
            if (pr >= 0) tbuf[pr * NHID + f0 + fl] = gelu_f(acc[t] + b);
        }
    }
}

// K4b: expert layer2. grid (64 e, 4 d-chunks of 32, 2 batch-strides).
// Thread: one d row (j&31), 8 token groups of 2. ybuf[pair][d].
__global__ __launch_bounds__(256) void expert_l2_kernel(
        const float* __restrict__ W2, const float* __restrict__ B2,
        const int* __restrict__ elist, const int* __restrict__ ecnt,
        const float* __restrict__ tbuf, float* __restrict__ ybuf) {
    const int e = blockIdx.x;
    const int d0 = blockIdx.y * 32;
    const int mb = blockIdx.z;
    const int n = ecnt[e];
    const int j = threadIdx.x;
    const int dl = j & 31;
    const int tg = j >> 5;  // 0..7, 2 tokens each
    const float* W2r = W2 + ((size_t)e * NDIM + d0 + dl) * NHID;
    const float b = B2[e * NDIM + d0 + dl];
    const int* le = elist + e * (NTOK * 2);
    __shared__ float ts_[TB * NHID];  // 32 KB
    __shared__ int prs[TB];
    for (int bt = mb; bt * TB < n; bt += 2) {
        const int nb = min(TB, n - bt * TB);
        __syncthreads();
        if (j < TB) prs[j] = (j < nb) ? le[bt * TB + j] : -1;
        __syncthreads();
        for (int i = j; i < nb * (NHID / 4); i += 256)
            ((float4*)ts_)[i] =
                ((const float4*)tbuf)[prs[i >> 7] * (NHID / 4) + (i & 127)];
        __syncthreads();
        float acc[2] = {0.f, 0.f};
        for (int k = 0; k < NHID; k += 4) {
            float4 w = *(const float4*)(W2r + k);
#pragma unroll
            for (int t = 0; t < 2; ++t) {
                const float* tr = ts_ + (tg * 2 + t) * NHID + k;
                acc[t] += w.x * tr[0] + w.y * tr[1] + w.z * tr[2] + w.w * tr[3];
            }
        }
#pragma unroll
        for (int t = 0; t < 2; ++t) {
            const int tt = tg * 2 + t;
            const int pr = prs[tt];
            if (pr >= 0) ybuf[pr * NDIM + d0 + dl] = gelu_f(acc[t] + b);
        }
    }
}

// K5: out[t,d] = w0*y[t,0,d] + w1*y[t,1,d]
__global__ __launch_bounds__(256) void combine_kernel(
        const float* __restrict__ ybuf, const float* __restrict__ wval,
        float* __restrict__ out) {
    const int i = blockIdx.x * 256 + threadIdx.x;
    const int t = i >> 7, d = i & (NDIM - 1);
    out[i] = wval[t * 2] * ybuf[t * 2 * NDIM + d]
           + wval[t * 2 + 1] * ybuf[(t * 2 + 1) * NDIM + d];
}

extern "C" void kernel_launch(void* const* d_in, const int* in_sizes, int n_in,
                              void* d_out, int out_size, void* d_ws, size_t ws_size,
                              hipStream_t stream) {
    const float* x   = (const float*)d_in[0];
    const float* gw1 = (const float*)d_in[1];
    const float* gb1 = (const float*)d_in[2];
    const float* gw2 = (const float*)d_in[3];
    const float* gb2 = (const float*)d_in[4];
    const float* gw3 = (const float*)d_in[5];
    const float* gb3 = (const float*)d_in[6];
    const float* W1  = (const float*)d_in[7];
    const float* B1  = (const float*)d_in[8];
    const float* W2  = (const float*)d_in[9];
    const float* B2  = (const float*)d_in[10];
    float* out = (float*)d_out;

    char* ws = (char*)d_ws;
    float* h1    = (float*)(ws);                        // [0,2MB)
    float* h2    = (float*)(ws + (2u << 20));           // [2,4MB)
    float* tbuf  = (float*)(ws);                        // [0,4MB) aliases h1/h2 (dead after gate3)
    float* ybuf  = (float*)(ws + (4u << 20));           // [4,5MB)
    int*   eidx  = (int*)  (ws + (5u << 20));           // 8 KB
    float* wval  = (float*)(ws + (5u << 20) + 8192);    // 8 KB
    int*   elist = (int*)  (ws + (5u << 20) + 16384);   // 512 KB
    int*   ecnt  = (int*)  (ws + (5u << 20) + 16384 + (NEXPERT * NTOK * 2 * 4));

    gate1_kernel<<<dim3(NTOK / 8, 2), 256, 0, stream>>>(x, gw1, gb1, h1);
    gate2_kernel<<<dim3(NTOK / 8, 4), 256, 0, stream>>>(h1, gw2, gb2, h2);
    gate3_top2_kernel<<<dim3(NTOK / 8), 256, 0, stream>>>(h2, gw3, gb3, eidx, wval);
    build_lists_kernel<<<dim3(NEXPERT), 256, 0, stream>>>(eidx, elist, ecnt);
    expert_l1_kernel<<<dim3(NEXPERT, 8, 2), 256, 0, stream>>>(x, W1, B1, elist, ecnt, tbuf);
    expert_l2_kernel<<<dim3(NEXPERT, 4, 2), 256, 0, stream>>>(W2, B2, elist, ecnt, tbuf, ybuf);
    combine_kernel<<<dim3(NTOK * NDIM / 256), 256, 0, stream>>>(ybuf, wval, out);
}

// Round 4
// 122.409 us; speedup vs baseline: 2.5541x; 2.5541x over previous
//
#include <hip/hip_runtime.h>
#include <math.h>

#define NDIM 128
#define NHID 512
#define NEXPERT 64
#define NTOK 1024

__device__ __forceinline__ float gelu_f(float v) {
    return 0.5f * v * (1.0f + erff(v * 0.7071067811865476f));
}

// Generic 64x64-tile f32 GEMM. C_z = A[M][K] @ B[K][N] restricted to k-range
// [z*klen,(z+1)*klen), z = blockIdx.z. act==1: C = gelu(C + bias) (full-K only).
// As staged transposed (As[kk][m]) so inner loop reads are float4.
__global__ __launch_bounds__(256) void gemm64_kernel(
        const float* __restrict__ A, const float* __restrict__ B,
        const float* __restrict__ bias, float* __restrict__ C,
        int K, int N, int klen, int act, long long cstride) {
    __shared__ float As[32][76];  // stride 76: 304B = 16*19 (aligned), mod32=12
    __shared__ float Bs[32][76];
    const int j = threadIdx.x;
    const int tx = j & 15, ty = j >> 4;
    const int m0 = blockIdx.x * 64, n0 = blockIdx.y * 64;
    const int kbase = blockIdx.z * klen;
    float acc[4][4];
#pragma unroll
    for (int i = 0; i < 4; ++i)
#pragma unroll
        for (int q = 0; q < 4; ++q) acc[i][q] = 0.f;

    for (int kc = 0; kc < klen; kc += 32) {
        __syncthreads();
        // stage A tile (64 m x 32 k), transposed into As[kk][m]
        for (int idx = j; idx < 512; idx += 256) {
            const int m = idx >> 3, c4 = idx & 7;
            float4 v = *(const float4*)(A + (size_t)(m0 + m) * K + kbase + kc + c4 * 4);
            As[c4 * 4 + 0][m] = v.x;
            As[c4 * 4 + 1][m] = v.y;
            As[c4 * 4 + 2][m] = v.z;
            As[c4 * 4 + 3][m] = v.w;
        }
        // stage B tile (32 k x 64 n), natural
        for (int idx = j; idx < 512; idx += 256) {
            const int kk = idx >> 4, c4 = idx & 15;
            *(float4*)&Bs[kk][c4 * 4] =
                *(const float4*)(B + (size_t)(kbase + kc + kk) * N + n0 + c4 * 4);
        }
        __syncthreads();
#pragma unroll
        for (int kk = 0; kk < 32; ++kk) {
            float4 a = *(float4*)&As[kk][ty * 4];
            float4 b = *(float4*)&Bs[kk][tx * 4];
            acc[0][0] += a.x * b.x; acc[0][1] += a.x * b.y; acc[0][2] += a.x * b.z; acc[0][3] += a.x * b.w;
            acc[1][0] += a.y * b.x; acc[1][1] += a.y * b.y; acc[1][2] += a.y * b.z; acc[1][3] += a.y * b.w;
            acc[2][0] += a.z * b.x; acc[2][1] += a.z * b.y; acc[2][2] += a.z * b.z; acc[2][3] += a.z * b.w;
            acc[3][0] += a.w * b.x; acc[3][1] += a.w * b.y; acc[3][2] += a.w * b.z; acc[3][3] += a.w * b.w;
        }
    }
    float* Cz = C + (size_t)blockIdx.z * cstride;
    if (act) {
        float4 bb = *(const float4*)(bias + n0 + tx * 4);
#pragma unroll
        for (int i = 0; i < 4; ++i) {
            float4 o;
            o.x = gelu_f(acc[i][0] + bb.x);
            o.y = gelu_f(acc[i][1] + bb.y);
            o.z = gelu_f(acc[i][2] + bb.z);
            o.w = gelu_f(acc[i][3] + bb.w);
            *(float4*)(Cz + (size_t)(m0 + ty * 4 + i) * N + n0 + tx * 4) = o;
        }
    } else {
#pragma unroll
        for (int i = 0; i < 4; ++i) {
            float4 o = make_float4(acc[i][0], acc[i][1], acc[i][2], acc[i][3]);
            *(float4*)(Cz + (size_t)(m0 + ty * 4 + i) * N + n0 + tx * 4) = o;
        }
    }
}

// h2 = gelu(h2p[0] + h2p[1] + gb2), float4-granular
__global__ __launch_bounds__(256) void combine2_kernel(
        const float* __restrict__ p, const float* __restrict__ gb2,
        float* __restrict__ h2) {
    const int i = blockIdx.x * 256 + threadIdx.x;  // float4 index, 131072 total
    float4 v0 = ((const float4*)p)[i];
    float4 v1 = ((const float4*)p)[(NTOK * NHID / 4) + i];
    float4 bb = ((const float4*)gb2)[i & (NHID / 4 - 1)];
    float4 o;
    o.x = gelu_f(v0.x + v1.x + bb.x);
    o.y = gelu_f(v0.y + v1.y + bb.y);
    o.z = gelu_f(v0.z + v1.z + bb.z);
    o.w = gelu_f(v0.w + v1.w + bb.w);
    ((float4*)h2)[i] = o;
}

// gate3: logits = h2 @ gw3 + gb3 (LDS-staged), sigmoid, top-2, normalize.
// 64 blocks x 16 tokens; lane = expert; wave = 4 tokens.
__global__ __launch_bounds__(256) void gate3_top2_kernel(
        const float* __restrict__ h2, const float* __restrict__ gw3,
        const float* __restrict__ gb3, int* __restrict__ eidx,
        float* __restrict__ wval) {
    __shared__ float hs[16][132];
    __shared__ float gs[128][72];
    const int j = threadIdx.x;
    const int t0 = blockIdx.x * 16;
    const int lane = j & 63;
    const int tg = j >> 6;  // 0..3 -> tokens tg*4..tg*4+3
    float acc[4] = {0.f, 0.f, 0.f, 0.f};
    for (int k0 = 0; k0 < NHID; k0 += 128) {
        __syncthreads();
        for (int idx = j; idx < 512; idx += 256) {  // 16 rows x 32 f4
            const int tok = idx >> 5, c4 = idx & 31;
            *(float4*)&hs[tok][c4 * 4] =
                *(const float4*)(h2 + (size_t)(t0 + tok) * NHID + k0 + c4 * 4);
        }
        for (int idx = j; idx < 2048; idx += 256) {  // 128 rows x 16 f4
            const int kk = idx >> 4, c4 = idx & 15;
            *(float4*)&gs[kk][c4 * 4] =
                *(const float4*)(gw3 + (size_t)(k0 + kk) * NEXPERT + c4 * 4);
        }
        __syncthreads();
        for (int kk = 0; kk < 128; ++kk) {
            const float g = gs[kk][lane];
#pragma unroll
            for (int i = 0; i < 4; ++i) acc[i] += hs[tg * 4 + i][kk] * g;
        }
    }
    const float bias = gb3[lane];
#pragma unroll
    for (int i = 0; i < 4; ++i) {
        const int t = t0 + tg * 4 + i;
        float s = 1.f / (1.f + expf(-(acc[i] + bias)));
        float v = s; int ix = lane;
#pragma unroll
        for (int off = 32; off >= 1; off >>= 1) {
            float ov = __shfl_xor(v, off);
            int oi = __shfl_xor(ix, off);
            if (ov > v || (ov == v && oi < ix)) { v = ov; ix = oi; }
        }
        const float v0 = v; const int i0 = ix;
        float v2 = (lane == i0) ? -1.f : s; int ix2 = lane;
#pragma unroll
        for (int off = 32; off >= 1; off >>= 1) {
            float ov = __shfl_xor(v2, off);
            int oi = __shfl_xor(ix2, off);
            if (ov > v2 || (ov == v2 && oi < ix2)) { v2 = ov; ix2 = oi; }
        }
        if (lane == 0) {
            float inv = 1.f / (v0 + v2);
            eidx[t * 2] = i0;  eidx[t * 2 + 1] = ix2;
            wval[t * 2] = v0 * inv;  wval[t * 2 + 1] = v2 * inv;
        }
    }
}

// deterministic per-expert lists via block scan (index order)
__global__ __launch_bounds__(256) void build_lists_kernel(
        const int* __restrict__ eidx, int* __restrict__ elist,
        int* __restrict__ ecnt) {
    const int e = blockIdx.x;
    const int j = threadIdx.x;
    __shared__ int cnts[256];
    int my[8];
    int mc = 0;
#pragma unroll
    for (int q = 0; q < 8; ++q) {
        int i = j * 8 + q;
        if (eidx[i] == e) my[mc++] = i;
    }
    cnts[j] = mc;
    __syncthreads();
    for (int off = 1; off < 256; off <<= 1) {
        int other = (j >= off) ? cnts[j - off] : 0;
        __syncthreads();
        cnts[j] += other;
        __syncthreads();
    }
    const int base = cnts[j] - mc;
    for (int q = 0; q < mc; ++q) elist[e * (NTOK * 2) + base + q] = my[q];
    if (j == 255) ecnt[e] = cnts[255];
}

// expert layer1: grid (64 e, 8 f-chunks). tile = 32 tokens x 64 f, K=128.
// Thread = 2 tokens x 4 f. B staged transposed (Bs[kk][f]).
__global__ __launch_bounds__(256) void expert_l1_kernel(
        const float* __restrict__ x, const float* __restrict__ W1,
        const float* __restrict__ B1, const int* __restrict__ elist,
        const int* __restrict__ ecnt, float* __restrict__ tbuf) {
    __shared__ float As[32][132];  // 528B rows: 16-aligned
    __shared__ float Bs[128][72];
    __shared__ int prs[32];
    const int e = blockIdx.x;
    const int f0 = blockIdx.y * 64;
    const int n = ecnt[e];
    const int* le = elist + e * (NTOK * 2);
    const float* W1e = W1 + (size_t)e * NHID * NDIM;
    const int j = threadIdx.x;
    const int tx = j & 15, ty = j >> 4;
    const int fl = j & 63, ks = j >> 6;
    const float4 bb = *(const float4*)(B1 + e * NHID + f0 + tx * 4);
    for (int bt = 0; bt * 32 < n; ++bt) {
        const int nb = min(32, n - bt * 32);
        __syncthreads();
        if (j < 32) prs[j] = (j < nb) ? le[bt * 32 + j] : -1;
        __syncthreads();
        // stage gathered x rows: 32 x 128 (32 f4/row)
        for (int idx = j; idx < 1024; idx += 256) {
            const int tok = idx >> 5, c4 = idx & 31;
            const int pr = prs[tok];
            float4 v = make_float4(0.f, 0.f, 0.f, 0.f);
            if (pr >= 0) v = ((const float4*)x)[(pr >> 1) * 32 + c4];
            *(float4*)&As[tok][c4 * 4] = v;
        }
        // stage W1 chunk transposed: row f = fl, k-segment ks*32
        {
            const float* wr = W1e + (size_t)(f0 + fl) * NDIM + ks * 32;
#pragma unroll
            for (int q = 0; q < 8; ++q) {
                float4 v = *(const float4*)(wr + q * 4);
                const int kk = ks * 32 + q * 4;
                Bs[kk + 0][fl] = v.x; Bs[kk + 1][fl] = v.y;
                Bs[kk + 2][fl] = v.z; Bs[kk + 3][fl] = v.w;
            }
        }
        __syncthreads();
        float acc[2][4] = {{0.f, 0.f, 0.f, 0.f}, {0.f, 0.f, 0.f, 0.f}};
#pragma unroll 4
        for (int kk = 0; kk < 128; ++kk) {
            const float a0 = As[ty * 2][kk];
            const float a1 = As[ty * 2 + 1][kk];
            float4 b = *(float4*)&Bs[kk][tx * 4];
            acc[0][0] += a0 * b.x; acc[0][1] += a0 * b.y; acc[0][2] += a0 * b.z; acc[0][3] += a0 * b.w;
            acc[1][0] += a1 * b.x; acc[1][1] += a1 * b.y; acc[1][2] += a1 * b.z; acc[1][3] += a1 * b.w;
        }
#pragma unroll
        for (int i = 0; i < 2; ++i) {
            const int pr = prs[ty * 2 + i];
            if (pr >= 0) {
                float4 o;
                o.x = gelu_f(acc[i][0] + bb.x);
                o.y = gelu_f(acc[i][1] + bb.y);
                o.z = gelu_f(acc[i][2] + bb.z);
                o.w = gelu_f(acc[i][3] + bb.w);
                ((float4*)tbuf)[pr * (NHID / 4) + (f0 >> 2) + tx] = o;
            }
        }
    }
}

// expert layer2: grid (64 e, 2 d-chunks, 2 k-splits). tile 32 tok x 64 d,
// K-half = 256 in 2 chunks of 128. Writes raw partial sums to pbuf.
__global__ __launch_bounds__(256) void expert_l2_kernel(
        const float* __restrict__ W2, const int* __restrict__ elist,
        const int* __restrict__ ecnt, const float* __restrict__ tbuf,
        float* __restrict__ pbuf) {
    __shared__ float As[32][132];
    __shared__ float Bs[128][72];
    __shared__ int prs[32];
    const int e = blockIdx.x;
    const int d0 = blockIdx.y * 64;
    const int kz = blockIdx.z;
    const int n = ecnt[e];
    const int* le = elist + e * (NTOK * 2);
    const float* W2e = W2 + (size_t)e * NDIM * NHID;
    const int j = threadIdx.x;
    const int tx = j & 15, ty = j >> 4;
    const int fl = j & 63, ks = j >> 6;
    for (int bt = 0; bt * 32 < n; ++bt) {
        const int nb = min(32, n - bt * 32);
        __syncthreads();
        if (j < 32) prs[j] = (j < nb) ? le[bt * 32 + j] : -1;
        __syncthreads();
        float acc[2][4] = {{0.f, 0.f, 0.f, 0.f}, {0.f, 0.f, 0.f, 0.f}};
        for (int kc = 0; kc < 2; ++kc) {
            const int k0 = kz * 256 + kc * 128;
            // stage gathered tbuf rows (32 x 128)
            for (int idx = j; idx < 1024; idx += 256) {
                const int tok = idx >> 5, c4 = idx & 31;
                const int pr = prs[tok];
                float4 v = make_float4(0.f, 0.f, 0.f, 0.f);
                if (pr >= 0) v = ((const float4*)tbuf)[pr * (NHID / 4) + (k0 >> 2) + c4];
                *(float4*)&As[tok][c4 * 4] = v;
            }
            // stage W2 chunk transposed: row d = fl
            {
                const float* wr = W2e + (size_t)(d0 + fl) * NHID + k0 + ks * 32;
#pragma unroll
                for (int q = 0; q < 8; ++q) {
                    float4 v = *(const float4*)(wr + q * 4);
                    const int kk = ks * 32 + q * 4;
                    Bs[kk + 0][fl] = v.x; Bs[kk + 1][fl] = v.y;
                    Bs[kk + 2][fl] = v.z; Bs[kk + 3][fl] = v.w;
                }
            }
            __syncthreads();
#pragma unroll 4
            for (int kk = 0; kk < 128; ++kk) {
                const float a0 = As[ty * 2][kk];
                const float a1 = As[ty * 2 + 1][kk];
                float4 b = *(float4*)&Bs[kk][tx * 4];
                acc[0][0] += a0 * b.x; acc[0][1] += a0 * b.y; acc[0][2] += a0 * b.z; acc[0][3] += a0 * b.w;
                acc[1][0] += a1 * b.x; acc[1][1] += a1 * b.y; acc[1][2] += a1 * b.z; acc[1][3] += a1 * b.w;
            }
            __syncthreads();
        }
#pragma unroll
        for (int i = 0; i < 2; ++i) {
            const int pr = prs[ty * 2 + i];
            if (pr >= 0) {
                float4 o = make_float4(acc[i][0], acc[i][1], acc[i][2], acc[i][3]);
                ((float4*)pbuf)[(size_t)kz * (NTOK * 2 * NDIM / 4) + pr * (NDIM / 4) + (d0 >> 2) + tx] = o;
            }
        }
    }
}

// final: out[t,d] = sum_kk wval[t,kk] * gelu(p0+p1+B2[e,d])
__global__ __launch_bounds__(256) void combine_kernel(
        const float* __restrict__ pbuf, const float* __restrict__ wval,
        const int* __restrict__ eidx, const float* __restrict__ B2,
        float* __restrict__ out) {
    const int i = blockIdx.x * 256 + threadIdx.x;
    const int t = i >> 7, d = i & (NDIM - 1);
    const int p0 = t * 2, p1 = t * 2 + 1;
    const int e0 = eidx[p0], e1 = eidx[p1];
    const int KS = NTOK * 2 * NDIM;
    float y0 = gelu_f(pbuf[p0 * NDIM + d] + pbuf[KS + p0 * NDIM + d] + B2[e0 * NDIM + d]);
    float y1 = gelu_f(pbuf[p1 * NDIM + d] + pbuf[KS + p1 * NDIM + d] + B2[e1 * NDIM + d]);
    out[i] = wval[p0] * y0 + wval[p1] * y1;
}

extern "C" void kernel_launch(void* const* d_in, const int* in_sizes, int n_in,
                              void* d_out, int out_size, void* d_ws, size_t ws_size,
                              hipStream_t stream) {
    const float* x   = (const float*)d_in[0];
    const float* gw1 = (const float*)d_in[1];
    const float* gb1 = (const float*)d_in[2];
    const float* gw2 = (const float*)d_in[3];
    const float* gb2 = (const float*)d_in[4];
    const float* gw3 = (const float*)d_in[5];
    const float* gb3 = (const float*)d_in[6];
    const float* W1  = (const float*)d_in[7];
    const float* B1  = (const float*)d_in[8];
    const float* W2  = (const float*)d_in[9];
    const float* B2  = (const float*)d_in[10];
    float* out = (float*)d_out;

    char* ws = (char*)d_ws;
    // [0,2MB) h1 | [2,6MB) h2p (2x 2MB) | [6,8MB) h2
    // tbuf aliases [0,4MB) (h1,h2p0 dead) ; pbuf aliases [4,6MB) (h2p1 dead)
    float* h1   = (float*)(ws);
    float* h2p  = (float*)(ws + (2ull << 20));
    float* h2   = (float*)(ws + (6ull << 20));
    float* tbuf = (float*)(ws);
    float* pbuf = (float*)(ws + (4ull << 20));
    int*   eidx  = (int*)  (ws + (8ull << 20));
    float* wval  = (float*)(ws + (8ull << 20) + 8192);
    int*   elist = (int*)  (ws + (8ull << 20) + 16384);
    int*   ecnt  = (int*)  (ws + (8ull << 20) + 16384 + NEXPERT * NTOK * 2 * 4);

    // gate MLP
    gemm64_kernel<<<dim3(16, 8, 1), 256, 0, stream>>>(x, gw1, gb1, h1, 128, NHID, 128, 1, 0);
    gemm64_kernel<<<dim3(16, 8, 2), 256, 0, stream>>>(h1, gw2, nullptr, h2p, NHID, NHID, 256, 0,
                                                      (long long)NTOK * NHID);
    combine2_kernel<<<dim3(NTOK * NHID / 4 / 256), 256, 0, stream>>>(h2p, gb2, h2);
    gate3_top2_kernel<<<dim3(NTOK / 16), 256, 0, stream>>>(h2, gw3, gb3, eidx, wval);
    build_lists_kernel<<<dim3(NEXPERT), 256, 0, stream>>>(eidx, elist, ecnt);
    // experts
    expert_l1_kernel<<<dim3(NEXPERT, 8), 256, 0, stream>>>(x, W1, B1, elist, ecnt, tbuf);
    expert_l2_kernel<<<dim3(NEXPERT, 2, 2), 256, 0, stream>>>(W2, elist, ecnt, tbuf, pbuf);
    combine_kernel<<<dim3(NTOK * NDIM / 256), 256, 0, stream>>>(pbuf, wval, eidx, B2, out);
}

// Round 5
// 89.305 us; speedup vs baseline: 3.5008x; 1.3707x over previous
//
#include <hip/hip_runtime.h>
#include <math.h>

#define NDIM 128
#define NHID 512
#define NEXPERT 64
#define NTOK 1024

__device__ __forceinline__ float gelu_f(float v) {
    return 0.5f * v * (1.0f + erff(v * 0.7071067811865476f));
}

// 64x64-tile f32 GEMM with register double-buffered staging.
// C_z = A[M][K] @ B[K][N] over k in [z*klen,(z+1)*klen). act: C=gelu(C+bias).
__global__ __launch_bounds__(256) void gemm64_kernel(
        const float* __restrict__ A, const float* __restrict__ B,
        const float* __restrict__ bias, float* __restrict__ C,
        int K, int N, int klen, int act, long long cstride) {
    __shared__ float As[32][76];  // transposed A chunk [kk][m]
    __shared__ float Bs[32][76];  // natural B chunk [kk][n]
    const int j = threadIdx.x;
    const int tx = j & 15, ty = j >> 4;
    const int m0 = blockIdx.x * 64, n0 = blockIdx.y * 64;
    const int kbase = blockIdx.z * klen;
    const int am = j >> 3, ac = j & 7;   // A: 64 m x 8 c4 (two halves)
    const int bk = j >> 4, bc = j & 15;  // B: 32 kk x 16 c4 (two halves)
    float acc[4][4];
#pragma unroll
    for (int i = 0; i < 4; ++i)
#pragma unroll
        for (int q = 0; q < 4; ++q) acc[i][q] = 0.f;

    float4 pa0, pa1, pb0, pb1;
#define GLOAD(kc)                                                                      \
    do {                                                                               \
        pa0 = *(const float4*)(A + (size_t)(m0 + am) * K + kbase + (kc) + ac * 4);     \
        pa1 = *(const float4*)(A + (size_t)(m0 + am + 32) * K + kbase + (kc) + ac * 4);\
        pb0 = *(const float4*)(B + (size_t)(kbase + (kc) + bk) * N + n0 + bc * 4);     \
        pb1 = *(const float4*)(B + (size_t)(kbase + (kc) + bk + 16) * N + n0 + bc * 4);\
    } while (0)

    GLOAD(0);
    for (int kc = 0; kc < klen; kc += 32) {
        __syncthreads();
        As[ac * 4 + 0][am] = pa0.x; As[ac * 4 + 1][am] = pa0.y;
        As[ac * 4 + 2][am] = pa0.z; As[ac * 4 + 3][am] = pa0.w;
        As[ac * 4 + 0][am + 32] = pa1.x; As[ac * 4 + 1][am + 32] = pa1.y;
        As[ac * 4 + 2][am + 32] = pa1.z; As[ac * 4 + 3][am + 32] = pa1.w;
        *(float4*)&Bs[bk][bc * 4] = pb0;
        *(float4*)&Bs[bk + 16][bc * 4] = pb1;
        __syncthreads();
        if (kc + 32 < klen) GLOAD(kc + 32);
#pragma unroll
        for (int kk = 0; kk < 32; ++kk) {
            float4 a = *(float4*)&As[kk][ty * 4];
            float4 b = *(float4*)&Bs[kk][tx * 4];
            acc[0][0] += a.x * b.x; acc[0][1] += a.x * b.y; acc[0][2] += a.x * b.z; acc[0][3] += a.x * b.w;
            acc[1][0] += a.y * b.x; acc[1][1] += a.y * b.y; acc[1][2] += a.y * b.z; acc[1][3] += a.y * b.w;
            acc[2][0] += a.z * b.x; acc[2][1] += a.z * b.y; acc[2][2] += a.z * b.z; acc[2][3] += a.z * b.w;
            acc[3][0] += a.w * b.x; acc[3][1] += a.w * b.y; acc[3][2] += a.w * b.z; acc[3][3] += a.w * b.w;
        }
    }
#undef GLOAD
    float* Cz = C + (size_t)blockIdx.z * cstride;
    if (act) {
        float4 bb = *(const float4*)(bias + n0 + tx * 4);
#pragma unroll
        for (int i = 0; i < 4; ++i) {
            float4 o;
            o.x = gelu_f(acc[i][0] + bb.x);
            o.y = gelu_f(acc[i][1] + bb.y);
            o.z = gelu_f(acc[i][2] + bb.z);
            o.w = gelu_f(acc[i][3] + bb.w);
            *(float4*)(Cz + (size_t)(m0 + ty * 4 + i) * N + n0 + tx * 4) = o;
        }
    } else {
#pragma unroll
        for (int i = 0; i < 4; ++i) {
            float4 o = make_float4(acc[i][0], acc[i][1], acc[i][2], acc[i][3]);
            *(float4*)(Cz + (size_t)(m0 + ty * 4 + i) * N + n0 + tx * 4) = o;
        }
    }
}

// gate3 (fused): h2 = gelu(h2p0 + h2p1 + gb2) staged to LDS, logits = h2@gw3+gb3,
// sigmoid, top-2 (ties->lower idx), normalize. 128 blocks x 8 tokens.
// Accumulation order identical to previous passing version (chunk-major, kk asc).
__global__ __launch_bounds__(256) void gate3_top2_kernel(
        const float* __restrict__ h2p, const float* __restrict__ gb2,
        const float* __restrict__ gw3, const float* __restrict__ gb3,
        int* __restrict__ eidx, float* __restrict__ wval) {
    __shared__ float hs[8][132];
    __shared__ float gs[128][76];
    const int j = threadIdx.x;
    const int t0 = blockIdx.x * 8;
    const int lane = j & 63;
    const int w = j >> 6;  // wave -> tokens w*2, w*2+1
    const int htok = j >> 5, hc4 = j & 31;  // hs staging: 8 tok x 32 f4
    const int gkk = j >> 4, gc4 = j & 15;   // gs staging: (16 kk x 16 f4) x8
    float acc[2] = {0.f, 0.f};
    float4 ph0, ph1, pg[8];
#define G3LOAD(k0)                                                                            \
    do {                                                                                      \
        ph0 = *(const float4*)(h2p + (size_t)(t0 + htok) * NHID + (k0) + hc4 * 4);            \
        ph1 = *(const float4*)(h2p + (size_t)NTOK * NHID + (size_t)(t0 + htok) * NHID + (k0) + hc4 * 4); \
        _Pragma("unroll")                                                                     \
        for (int u = 0; u < 8; ++u)                                                           \
            pg[u] = *(const float4*)(gw3 + (size_t)((k0) + gkk + u * 16) * NEXPERT + gc4 * 4);\
    } while (0)

    G3LOAD(0);
    for (int k0 = 0; k0 < NHID; k0 += 128) {
        __syncthreads();
        {
            float4 bb = *(const float4*)(gb2 + k0 + hc4 * 4);
            float4 o;
            o.x = gelu_f(ph0.x + ph1.x + bb.x);
            o.y = gelu_f(ph0.y + ph1.y + bb.y);
            o.z = gelu_f(ph0.z + ph1.z + bb.z);
            o.w = gelu_f(ph0.w + ph1.w + bb.w);
            *(float4*)&hs[htok][hc4 * 4] = o;
#pragma unroll
            for (int u = 0; u < 8; ++u)
                *(float4*)&gs[gkk + u * 16][gc4 * 4] = pg[u];
        }
        __syncthreads();
        if (k0 + 128 < NHID) G3LOAD(k0 + 128);
        for (int kk = 0; kk < 128; ++kk) {
            const float g = gs[kk][lane];
            acc[0] += hs[w * 2][kk] * g;
            acc[1] += hs[w * 2 + 1][kk] * g;
        }
    }
#undef G3LOAD
    const float bias = gb3[lane];
#pragma unroll
    for (int i = 0; i < 2; ++i) {
        const int t = t0 + w * 2 + i;
        float s = 1.f / (1.f + expf(-(acc[i] + bias)));
        float v = s; int ix = lane;
#pragma unroll
        for (int off = 32; off >= 1; off >>= 1) {
            float ov = __shfl_xor(v, off);
            int oi = __shfl_xor(ix, off);
            if (ov > v || (ov == v && oi < ix)) { v = ov; ix = oi; }
        }
        const float v0 = v; const int i0 = ix;
        float v2 = (lane == i0) ? -1.f : s; int ix2 = lane;
#pragma unroll
        for (int off = 32; off >= 1; off >>= 1) {
            float ov = __shfl_xor(v2, off);
            int oi = __shfl_xor(ix2, off);
            if (ov > v2 || (ov == v2 && oi < ix2)) { v2 = ov; ix2 = oi; }
        }
        if (lane == 0) {
            float inv = 1.f / (v0 + v2);
            eidx[t * 2] = i0;  eidx[t * 2 + 1] = ix2;
            wval[t * 2] = v0 * inv;  wval[t * 2 + 1] = v2 * inv;
        }
    }
}

// deterministic per-expert lists via block scan (index order)
__global__ __launch_bounds__(256) void build_lists_kernel(
        const int* __restrict__ eidx, int* __restrict__ elist,
        int* __restrict__ ecnt) {
    const int e = blockIdx.x;
    const int j = threadIdx.x;
    __shared__ int cnts[256];
    int my[8];
    int mc = 0;
#pragma unroll
    for (int q = 0; q < 8; ++q) {
        int i = j * 8 + q;
        if (eidx[i] == e) my[mc++] = i;
    }
    cnts[j] = mc;
    __syncthreads();
    for (int off = 1; off < 256; off <<= 1) {
        int other = (j >= off) ? cnts[j - off] : 0;
        __syncthreads();
        cnts[j] += other;
        __syncthreads();
    }
    const int base = cnts[j] - mc;
    for (int q = 0; q < mc; ++q) elist[e * (NTOK * 2) + base + q] = my[q];
    if (j == 255) ecnt[e] = cnts[255];
}

// expert layer1: grid (64 e, 8 f-chunks). tile 32 tok x 64 f, K=128.
// W1 panel staged ONCE per block; only the x-gather repeats per batch.
__global__ __launch_bounds__(256) void expert_l1_kernel(
        const float* __restrict__ x, const float* __restrict__ W1,
        const float* __restrict__ B1, const int* __restrict__ elist,
        const int* __restrict__ ecnt, float* __restrict__ tbuf) {
    __shared__ float As[32][132];   // gathered x rows [tok][k]
    __shared__ float Bs[128][72];   // W1 chunk transposed [kk][f]
    __shared__ int prs[32];
    const int e = blockIdx.x;
    const int f0 = blockIdx.y * 64;
    const int n = ecnt[e];
    const int* le = elist + e * (NTOK * 2);
    const float* W1e = W1 + (size_t)e * NHID * NDIM;
    const int j = threadIdx.x;
    const int tx = j & 15, ty = j >> 4;
    const int fl = j & 63, ks = j >> 6;
    // stage W1 panel once
    {
        const float* wr = W1e + (size_t)(f0 + fl) * NDIM + ks * 32;
#pragma unroll
        for (int q = 0; q < 8; ++q) {
            float4 v = *(const float4*)(wr + q * 4);
            const int kk = ks * 32 + q * 4;
            Bs[kk + 0][fl] = v.x; Bs[kk + 1][fl] = v.y;
            Bs[kk + 2][fl] = v.z; Bs[kk + 3][fl] = v.w;
        }
    }
    const float4 bb = *(const float4*)(B1 + e * NHID + f0 + tx * 4);
    for (int bt = 0; bt * 32 < n; ++bt) {
        const int nb = min(32, n - bt * 32);
        __syncthreads();
        if (j < 32) prs[j] = (j < nb) ? le[bt * 32 + j] : -1;
        __syncthreads();
        for (int idx = j; idx < 1024; idx += 256) {
            const int tok = idx >> 5, c4 = idx & 31;
            const int pr = prs[tok];
            float4 v = make_float4(0.f, 0.f, 0.f, 0.f);
            if (pr >= 0) v = ((const float4*)x)[(pr >> 1) * 32 + c4];
            *(float4*)&As[tok][c4 * 4] = v;
        }
        __syncthreads();
        float acc[2][4] = {{0.f, 0.f, 0.f, 0.f}, {0.f, 0.f, 0.f, 0.f}};
#pragma unroll 8
        for (int kk = 0; kk < 128; ++kk) {
            const float a0 = As[ty * 2][kk];
            const float a1 = As[ty * 2 + 1][kk];
            float4 b = *(float4*)&Bs[kk][tx * 4];
            acc[0][0] += a0 * b.x; acc[0][1] += a0 * b.y; acc[0][2] += a0 * b.z; acc[0][3] += a0 * b.w;
            acc[1][0] += a1 * b.x; acc[1][1] += a1 * b.y; acc[1][2] += a1 * b.z; acc[1][3] += a1 * b.w;
        }
#pragma unroll
        for (int i = 0; i < 2; ++i) {
            const int pr = prs[ty * 2 + i];
            if (pr >= 0) {
                float4 o;
                o.x = gelu_f(acc[i][0] + bb.x);
                o.y = gelu_f(acc[i][1] + bb.y);
                o.z = gelu_f(acc[i][2] + bb.z);
                o.w = gelu_f(acc[i][3] + bb.w);
                ((float4*)tbuf)[pr * (NHID / 4) + (f0 >> 2) + tx] = o;
            }
        }
    }
}

// expert layer2: grid (64 e, 2 d-chunks, 4 k-splits of 128). tile 32 tok x 64 d.
// W2 chunk staged once per block; raw partials -> pbuf[kz].
__global__ __launch_bounds__(256) void expert_l2_kernel(
        const float* __restrict__ W2, const int* __restrict__ elist,
        const int* __restrict__ ecnt, const float* __restrict__ tbuf,
        float* __restrict__ pbuf) {
    __shared__ float As[32][132];
    __shared__ float Bs[128][72];
    __shared__ int prs[32];
    const int e = blockIdx.x;
    const int d0 = blockIdx.y * 64;
    const int kz = blockIdx.z;
    const int k0 = kz * 128;
    const int n = ecnt[e];
    const int* le = elist + e * (NTOK * 2);
    const float* W2e = W2 + (size_t)e * NDIM * NHID;
    const int j = threadIdx.x;
    const int tx = j & 15, ty = j >> 4;
    const int fl = j & 63, ks = j >> 6;
    {
        const float* wr = W2e + (size_t)(d0 + fl) * NHID + k0 + ks * 32;
#pragma unroll
        for (int q = 0; q < 8; ++q) {
            float4 v = *(const float4*)(wr + q * 4);
            const int kk = ks * 32 + q * 4;
            Bs[kk + 0][fl] = v.x; Bs[kk + 1][fl] = v.y;
            Bs[kk + 2][fl] = v.z; Bs[kk + 3][fl] = v.w;
        }
    }
    for (int bt = 0; bt * 32 < n; ++bt) {
        const int nb = min(32, n - bt * 32);
        __syncthreads();
        if (j < 32) prs[j] = (j < nb) ? le[bt * 32 + j] : -1;
        __syncthreads();
        for (int idx = j; idx < 1024; idx += 256) {
            const int tok = idx >> 5, c4 = idx & 31;
            const int pr = prs[tok];
            float4 v = make_float4(0.f, 0.f, 0.f, 0.f);
            if (pr >= 0) v = ((const float4*)tbuf)[pr * (NHID / 4) + (k0 >> 2) + c4];
            *(float4*)&As[tok][c4 * 4] = v;
        }
        __syncthreads();
        float acc[2][4] = {{0.f, 0.f, 0.f, 0.f}, {0.f, 0.f, 0.f, 0.f}};
#pragma unroll 8
        for (int kk = 0; kk < 128; ++kk) {
            const float a0 = As[ty * 2][kk];
            const float a1 = As[ty * 2 + 1][kk];
            float4 b = *(float4*)&Bs[kk][tx * 4];
            acc[0][0] += a0 * b.x; acc[0][1] += a0 * b.y; acc[0][2] += a0 * b.z; acc[0][3] += a0 * b.w;
            acc[1][0] += a1 * b.x; acc[1][1] += a1 * b.y; acc[1][2] += a1 * b.z; acc[1][3] += a1 * b.w;
        }
#pragma unroll
        for (int i = 0; i < 2; ++i) {
            const int pr = prs[ty * 2 + i];
            if (pr >= 0) {
                float4 o = make_float4(acc[i][0], acc[i][1], acc[i][2], acc[i][3]);
                ((float4*)pbuf)[(size_t)kz * (NTOK * 2 * NDIM / 4) + pr * (NDIM / 4) + (d0 >> 2) + tx] = o;
            }
        }
    }
}

// final: out[t,d] = sum_k wval[t,k] * gelu(sum_kz pbuf[kz] + B2[e,d])
__global__ __launch_bounds__(256) void combine_kernel(
        const float* __restrict__ pbuf, const float* __restrict__ wval,
        const int* __restrict__ eidx, const float* __restrict__ B2,
        float* __restrict__ out) {
    const int i = blockIdx.x * 256 + threadIdx.x;
    const int t = i >> 7, d = i & (NDIM - 1);
    const int KS = NTOK * 2 * NDIM;
    float y[2];
#pragma unroll
    for (int k = 0; k < 2; ++k) {
        const int p = t * 2 + k;
        float s = pbuf[p * NDIM + d] + pbuf[KS + p * NDIM + d]
                + pbuf[2 * KS + p * NDIM + d] + pbuf[3 * KS + p * NDIM + d]
                + B2[eidx[p] * NDIM + d];
        y[k] = gelu_f(s);
    }
    out[i] = wval[t * 2] * y[0] + wval[t * 2 + 1] * y[1];
}

extern "C" void kernel_launch(void* const* d_in, const int* in_sizes, int n_in,
                              void* d_out, int out_size, void* d_ws, size_t ws_size,
                              hipStream_t stream) {
    const float* x   = (const float*)d_in[0];
    const float* gw1 = (const float*)d_in[1];
    const float* gb1 = (const float*)d_in[2];
    const float* gw2 = (const float*)d_in[3];
    const float* gb2 = (const float*)d_in[4];
    const float* gw3 = (const float*)d_in[5];
    const float* gb3 = (const float*)d_in[6];
    const float* W1  = (const float*)d_in[7];
    const float* B1  = (const float*)d_in[8];
    const float* W2  = (const float*)d_in[9];
    const float* B2  = (const float*)d_in[10];
    float* out = (float*)d_out;

    char* ws = (char*)d_ws;
    // [0,2MB) h1 | [2,6MB) h2p (2x2MB) | tbuf aliases [0,4MB) after gate3 |
    // pbuf [6,10MB) (4 partials x 1MB) | control at 10MB+
    float* h1   = (float*)(ws);
    float* h2p  = (float*)(ws + (2ull << 20));
    float* tbuf = (float*)(ws);
    float* pbuf = (float*)(ws + (6ull << 20));
    int*   eidx  = (int*)  (ws + (10ull << 20));
    float* wval  = (float*)(ws + (10ull << 20) + 8192);
    int*   elist = (int*)  (ws + (10ull << 20) + 16384);
    int*   ecnt  = (int*)  (ws + (10ull << 20) + 16384 + NEXPERT * NTOK * 2 * 4);

    gemm64_kernel<<<dim3(16, 8, 1), 256, 0, stream>>>(x, gw1, gb1, h1, 128, NHID, 128, 1, 0);
    gemm64_kernel<<<dim3(16, 8, 2), 256, 0, stream>>>(h1, gw2, nullptr, h2p, NHID, NHID, 256, 0,
                                                      (long long)NTOK * NHID);
    gate3_top2_kernel<<<dim3(NTOK / 8), 256, 0, stream>>>(h2p, gb2, gw3, gb3, eidx, wval);
    build_lists_kernel<<<dim3(NEXPERT), 256, 0, stream>>>(eidx, elist, ecnt);
    expert_l1_kernel<<<dim3(NEXPERT, 8), 256, 0, stream>>>(x, W1, B1, elist, ecnt, tbuf);
    expert_l2_kernel<<<dim3(NEXPERT, 2, 4), 256, 0, stream>>>(W2, elist, ecnt, tbuf, pbuf);
    combine_kernel<<<dim3(NTOK * NDIM / 256), 256, 0, stream>>>(pbuf, wval, eidx, B2, out);
}

// Round 6
// 78.371 us; speedup vs baseline: 3.9892x; 1.1395x over previous
//
#include <hip/hip_runtime.h>
#include <math.h>

#define NDIM 128
#define NHID 512
#define NEXPERT 64
#define NTOK 1024
#define NPAIR (NTOK * 2)

typedef __attribute__((ext_vector_type(8))) short short8_t;
typedef __attribute__((ext_vector_type(4))) float f32x4;

__device__ __forceinline__ float gelu_f(float v) {
    return 0.5f * v * (1.0f + erff(v * 0.7071067811865476f));
}

// f32 -> bf16 RNE
__device__ __forceinline__ unsigned short f2bf(float f) {
    union { float f; unsigned u; } v; v.f = f;
    unsigned r = v.u + 0x7FFFu + ((v.u >> 16) & 1u);
    return (unsigned short)(r >> 16);
}

// ---------------- gating (all f32) ----------------

// 64x64-tile f32 GEMM, register double-buffered staging.
// C_z = A[M][K] @ B[K][N] over k in [z*klen,(z+1)*klen). act: C=gelu(C+bias).
__global__ __launch_bounds__(256) void gemm64_kernel(
        const float* __restrict__ A, const float* __restrict__ B,
        const float* __restrict__ bias, float* __restrict__ C,
        int K, int N, int klen, int act, long long cstride) {
    __shared__ float As[32][76];
    __shared__ float Bs[32][76];
    const int j = threadIdx.x;
    const int tx = j & 15, ty = j >> 4;
    const int m0 = blockIdx.x * 64, n0 = blockIdx.y * 64;
    const int kbase = blockIdx.z * klen;
    const int am = j >> 3, ac = j & 7;
    const int bk = j >> 4, bc = j & 15;
    float acc[4][4];
#pragma unroll
    for (int i = 0; i < 4; ++i)
#pragma unroll
        for (int q = 0; q < 4; ++q) acc[i][q] = 0.f;

    float4 pa0, pa1, pb0, pb1;
#define GLOAD(kc)                                                                      \
    do {                                                                               \
        pa0 = *(const float4*)(A + (size_t)(m0 + am) * K + kbase + (kc) + ac * 4);     \
        pa1 = *(const float4*)(A + (size_t)(m0 + am + 32) * K + kbase + (kc) + ac * 4);\
        pb0 = *(const float4*)(B + (size_t)(kbase + (kc) + bk) * N + n0 + bc * 4);     \
        pb1 = *(const float4*)(B + (size_t)(kbase + (kc) + bk + 16) * N + n0 + bc * 4);\
    } while (0)

    GLOAD(0);
    for (int kc = 0; kc < klen; kc += 32) {
        __syncthreads();
        As[ac * 4 + 0][am] = pa0.x; As[ac * 4 + 1][am] = pa0.y;
        As[ac * 4 + 2][am] = pa0.z; As[ac * 4 + 3][am] = pa0.w;
        As[ac * 4 + 0][am + 32] = pa1.x; As[ac * 4 + 1][am + 32] = pa1.y;
        As[ac * 4 + 2][am + 32] = pa1.z; As[ac * 4 + 3][am + 32] = pa1.w;
        *(float4*)&Bs[bk][bc * 4] = pb0;
        *(float4*)&Bs[bk + 16][bc * 4] = pb1;
        __syncthreads();
        if (kc + 32 < klen) GLOAD(kc + 32);
#pragma unroll
        for (int kk = 0; kk < 32; ++kk) {
            float4 a = *(float4*)&As[kk][ty * 4];
            float4 b = *(float4*)&Bs[kk][tx * 4];
            acc[0][0] += a.x * b.x; acc[0][1] += a.x * b.y; acc[0][2] += a.x * b.z; acc[0][3] += a.x * b.w;
            acc[1][0] += a.y * b.x; acc[1][1] += a.y * b.y; acc[1][2] += a.y * b.z; acc[1][3] += a.y * b.w;
            acc[2][0] += a.z * b.x; acc[2][1] += a.z * b.y; acc[2][2] += a.z * b.z; acc[2][3] += a.z * b.w;
            acc[3][0] += a.w * b.x; acc[3][1] += a.w * b.y; acc[3][2] += a.w * b.z; acc[3][3] += a.w * b.w;
        }
    }
#undef GLOAD
    float* Cz = C + (size_t)blockIdx.z * cstride;
    if (act) {
        float4 bb = *(const float4*)(bias + n0 + tx * 4);
#pragma unroll
        for (int i = 0; i < 4; ++i) {
            float4 o;
            o.x = gelu_f(acc[i][0] + bb.x);
            o.y = gelu_f(acc[i][1] + bb.y);
            o.z = gelu_f(acc[i][2] + bb.z);
            o.w = gelu_f(acc[i][3] + bb.w);
            *(float4*)(Cz + (size_t)(m0 + ty * 4 + i) * N + n0 + tx * 4) = o;
        }
    } else {
#pragma unroll
        for (int i = 0; i < 4; ++i) {
            float4 o = make_float4(acc[i][0], acc[i][1], acc[i][2], acc[i][3]);
            *(float4*)(Cz + (size_t)(m0 + ty * 4 + i) * N + n0 + tx * 4) = o;
        }
    }
}

// gate3: h2 = gelu(sum of 4 h2 partials + gb2) staged to LDS; logits = h2@gw3+gb3;
// sigmoid; top-2 (ties -> lower index); normalize. 64 blocks x 16 tokens.
__global__ __launch_bounds__(256) void gate3_top2_kernel(
        const float* __restrict__ h2p, const float* __restrict__ gb2,
        const float* __restrict__ gw3, const float* __restrict__ gb3,
        int* __restrict__ eidx, float* __restrict__ wval) {
    __shared__ float hs[16][132];
    __shared__ float gs[128][72];
    const int j = threadIdx.x;
    const int t0 = blockIdx.x * 16;
    const int lane = j & 63;
    const int w = j >> 6;  // wave -> tokens w*4 .. w*4+3
    const size_t PS = (size_t)NTOK * NHID;
    float acc[4] = {0.f, 0.f, 0.f, 0.f};
    for (int k0 = 0; k0 < NHID; k0 += 128) {
        __syncthreads();
        for (int idx = j; idx < 512; idx += 256) {  // 16 tok x 32 f4
            const int tok = idx >> 5, c4 = idx & 31;
            const size_t off = (size_t)(t0 + tok) * NHID + k0 + c4 * 4;
            float4 p0 = *(const float4*)(h2p + off);
            float4 p1 = *(const float4*)(h2p + PS + off);
            float4 p2 = *(const float4*)(h2p + 2 * PS + off);
            float4 p3 = *(const float4*)(h2p + 3 * PS + off);
            float4 bb = *(const float4*)(gb2 + k0 + c4 * 4);
            float4 o;
            o.x = gelu_f(p0.x + p1.x + p2.x + p3.x + bb.x);
            o.y = gelu_f(p0.y + p1.y + p2.y + p3.y + bb.y);
            o.z = gelu_f(p0.z + p1.z + p2.z + p3.z + bb.z);
            o.w = gelu_f(p0.w + p1.w + p2.w + p3.w + bb.w);
            *(float4*)&hs[tok][c4 * 4] = o;
        }
        for (int idx = j; idx < 2048; idx += 256) {  // 128 kk x 16 f4
            const int kk = idx >> 4, c4 = idx & 15;
            *(float4*)&gs[kk][c4 * 4] =
                *(const float4*)(gw3 + (size_t)(k0 + kk) * NEXPERT + c4 * 4);
        }
        __syncthreads();
        for (int kk = 0; kk < 128; ++kk) {
            const float g = gs[kk][lane];
#pragma unroll
            for (int i = 0; i < 4; ++i) acc[i] += hs[w * 4 + i][kk] * g;
        }
    }
    const float bias = gb3[lane];
#pragma unroll
    for (int i = 0; i < 4; ++i) {
        const int t = t0 + w * 4 + i;
        float s = 1.f / (1.f + expf(-(acc[i] + bias)));
        float v = s; int ix = lane;
#pragma unroll
        for (int off = 32; off >= 1; off >>= 1) {
            float ov = __shfl_xor(v, off);
            int oi = __shfl_xor(ix, off);
            if (ov > v || (ov == v && oi < ix)) { v = ov; ix = oi; }
        }
        const float v0 = v; const int i0 = ix;
        float v2 = (lane == i0) ? -1.f : s; int ix2 = lane;
#pragma unroll
        for (int off = 32; off >= 1; off >>= 1) {
            float ov = __shfl_xor(v2, off);
            int oi = __shfl_xor(ix2, off);
            if (ov > v2 || (ov == v2 && oi < ix2)) { v2 = ov; ix2 = oi; }
        }
        if (lane == 0) {
            float inv = 1.f / (v0 + v2);
            eidx[t * 2] = i0;  eidx[t * 2 + 1] = ix2;
            wval[t * 2] = v0 * inv;  wval[t * 2 + 1] = v2 * inv;
        }
    }
}

// deterministic per-expert lists via block scan (index order)
__global__ __launch_bounds__(256) void build_lists_kernel(
        const int* __restrict__ eidx, int* __restrict__ elist,
        int* __restrict__ ecnt) {
    const int e = blockIdx.x;
    const int j = threadIdx.x;
    __shared__ int cnts[256];
    int my[8];
    int mc = 0;
#pragma unroll
    for (int q = 0; q < 8; ++q) {
        int i = j * 8 + q;
        if (eidx[i] == e) my[mc++] = i;
    }
    cnts[j] = mc;
    __syncthreads();
    for (int off = 1; off < 256; off <<= 1) {
        int other = (j >= off) ? cnts[j - off] : 0;
        __syncthreads();
        cnts[j] += other;
        __syncthreads();
    }
    const int base = cnts[j] - mc;
    for (int q = 0; q < mc; ++q) elist[e * NPAIR + base + q] = my[q];
    if (j == 255) ecnt[e] = cnts[255];
}

// ---------------- experts (bf16 MFMA) ----------------
// MFMA 16x16x32 bf16 fragment maps (gfx950, verified):
//   A: lane holds A[m = lane&15][k = (lane>>4)*8 + e], e=0..7  (16B LDS read)
//   B: lane holds B[k = (lane>>4)*8 + e][n = lane&15]
//   C: reg r -> row = (lane>>4)*4 + r, col = lane&15
// LDS rows padded to 272 B (16B-aligned, 2-way bank alias only).

#define L1_ROWSH 136  // shorts per row (272 B)

// expert layer1: grid (64 e, 8 f-chunks of 64). tile 32 tok x 64 f, K=128.
// tbuf (bf16) [pair][512] = gelu(x @ W1^T + B1)
__global__ __launch_bounds__(256) void expert_l1_kernel(
        const float* __restrict__ x, const float* __restrict__ W1,
        const float* __restrict__ B1, const int* __restrict__ elist,
        const int* __restrict__ ecnt, unsigned short* __restrict__ tbuf) {
    __shared__ short As[32 * L1_ROWSH];   // x gathered, bf16 [tok][k]
    __shared__ short Bs[64 * L1_ROWSH];   // W1 panel,   bf16 [f][k]
    __shared__ int prs[32];
    const int e = blockIdx.x;
    const int f0 = blockIdx.y * 64;
    const int n = ecnt[e];
    const int* le = elist + e * NPAIR;
    const float* W1e = W1 + (size_t)e * NHID * NDIM;
    const int j = threadIdx.x;
    const int lane = j & 63;
    const int w = j >> 6;
    char* Asc = (char*)As;
    char* Bsc = (char*)Bs;
    // stage W1 panel once: 64 f x 32 f4
    for (int idx = j; idx < 2048; idx += 256) {
        const int f = idx >> 5, c4 = idx & 31;
        float4 v = *(const float4*)(W1e + (size_t)(f0 + f) * NDIM + c4 * 4);
        short4 s; s.x = f2bf(v.x); s.y = f2bf(v.y); s.z = f2bf(v.z); s.w = f2bf(v.w);
        *(short4*)(Bsc + f * 272 + c4 * 8) = s;
    }
    const float bbias = B1[e * NHID + f0 + w * 16 + (lane & 15)];
    for (int bt = 0; bt * 32 < n; ++bt) {
        const int nb = min(32, n - bt * 32);
        __syncthreads();
        if (j < 32) prs[j] = (j < nb) ? le[bt * 32 + j] : -1;
        __syncthreads();
        // gather x rows -> bf16 LDS: 32 tok x 32 f4
        for (int idx = j; idx < 1024; idx += 256) {
            const int tok = idx >> 5, c4 = idx & 31;
            const int pr = prs[tok];
            float4 v = make_float4(0.f, 0.f, 0.f, 0.f);
            if (pr >= 0) v = ((const float4*)x)[(size_t)(pr >> 1) * 32 + c4];
            short4 s; s.x = f2bf(v.x); s.y = f2bf(v.y); s.z = f2bf(v.z); s.w = f2bf(v.w);
            *(short4*)(Asc + tok * 272 + c4 * 8) = s;
        }
        __syncthreads();
        f32x4 acc[2];
        acc[0] = (f32x4){0.f, 0.f, 0.f, 0.f};
        acc[1] = (f32x4){0.f, 0.f, 0.f, 0.f};
        const int acol = ((lane >> 4) << 4);  // k-seg byte offset
        const int brow = w * 16 + (lane & 15);
#pragma unroll
        for (int ks = 0; ks < 4; ++ks) {
            short8_t b = *(short8_t*)(Bsc + brow * 272 + ks * 64 + acol);
#pragma unroll
            for (int mt = 0; mt < 2; ++mt) {
                short8_t a = *(short8_t*)(Asc + (mt * 16 + (lane & 15)) * 272 + ks * 64 + acol);
                acc[mt] = __builtin_amdgcn_mfma_f32_16x16x32_bf16(a, b, acc[mt], 0, 0, 0);
            }
        }
        const int fcol = f0 + w * 16 + (lane & 15);
#pragma unroll
        for (int mt = 0; mt < 2; ++mt) {
#pragma unroll
            for (int r = 0; r < 4; ++r) {
                const int tok = mt * 16 + ((lane >> 4) << 2) + r;
                const int pr = prs[tok];
                if (pr >= 0)
                    tbuf[(size_t)pr * NHID + fcol] = f2bf(gelu_f(acc[mt][r] + bbias));
            }
        }
    }
}

// expert layer2: grid (64 e, 2 d-chunks of 64, 4 k-splits of 128).
// pbuf[kz][pair][128] f32 partial = t @ W2^T (k-range only)
__global__ __launch_bounds__(256) void expert_l2_kernel(
        const float* __restrict__ W2, const int* __restrict__ elist,
        const int* __restrict__ ecnt, const unsigned short* __restrict__ tbuf,
        float* __restrict__ pbuf) {
    __shared__ short As[32 * L1_ROWSH];   // t gathered, bf16 [tok][k]
    __shared__ short Bs[64 * L1_ROWSH];   // W2 panel,   bf16 [d][k]
    __shared__ int prs[32];
    const int e = blockIdx.x;
    const int d0 = blockIdx.y * 64;
    const int kz = blockIdx.z;
    const int k0 = kz * 128;
    const int n = ecnt[e];
    const int* le = elist + e * NPAIR;
    const float* W2e = W2 + (size_t)e * NDIM * NHID;
    const int j = threadIdx.x;
    const int lane = j & 63;
    const int w = j >> 6;
    char* Asc = (char*)As;
    char* Bsc = (char*)Bs;
    // stage W2 panel once: 64 d x 32 f4 (k in [k0,k0+128))
    for (int idx = j; idx < 2048; idx += 256) {
        const int d = idx >> 5, c4 = idx & 31;
        float4 v = *(const float4*)(W2e + (size_t)(d0 + d) * NHID + k0 + c4 * 4);
        short4 s; s.x = f2bf(v.x); s.y = f2bf(v.y); s.z = f2bf(v.z); s.w = f2bf(v.w);
        *(short4*)(Bsc + d * 272 + c4 * 8) = s;
    }
    float* pz = pbuf + (size_t)kz * NPAIR * NDIM;
    for (int bt = 0; bt * 32 < n; ++bt) {
        const int nb = min(32, n - bt * 32);
        __syncthreads();
        if (j < 32) prs[j] = (j < nb) ? le[bt * 32 + j] : -1;
        __syncthreads();
        // gather t rows (already bf16): 32 tok x 16 chunks of 8 bf16
        for (int idx = j; idx < 512; idx += 256) {
            const int tok = idx >> 4, c8 = idx & 15;
            const int pr = prs[tok];
            short8_t v = (short8_t)(short)0;
            if (pr >= 0) v = *(const short8_t*)(tbuf + (size_t)pr * NHID + k0 + c8 * 8);
            *(short8_t*)(Asc + tok * 272 + c8 * 16) = v;
        }
        __syncthreads();
        f32x4 acc[2];
        acc[0] = (f32x4){0.f, 0.f, 0.f, 0.f};
        acc[1] = (f32x4){0.f, 0.f, 0.f, 0.f};
        const int acol = ((lane >> 4) << 4);
        const int brow = w * 16 + (lane & 15);
#pragma unroll
        for (int ks = 0; ks < 4; ++ks) {
            short8_t b = *(short8_t*)(Bsc + brow * 272 + ks * 64 + acol);
#pragma unroll
            for (int mt = 0; mt < 2; ++mt) {
                short8_t a = *(short8_t*)(Asc + (mt * 16 + (lane & 15)) * 272 + ks * 64 + acol);
                acc[mt] = __builtin_amdgcn_mfma_f32_16x16x32_bf16(a, b, acc[mt], 0, 0, 0);
            }
        }
        const int dcol = d0 + w * 16 + (lane & 15);
#pragma unroll
        for (int mt = 0; mt < 2; ++mt) {
#pragma unroll
            for (int r = 0; r < 4; ++r) {
                const int tok = mt * 16 + ((lane >> 4) << 2) + r;
                const int pr = prs[tok];
                if (pr >= 0) pz[(size_t)pr * NDIM + dcol] = acc[mt][r];
            }
        }
    }
}

// final: out[t,d] = sum_k wval[t,k] * gelu(sum_kz pbuf[kz] + B2[e,d])
__global__ __launch_bounds__(256) void combine_kernel(
        const float* __restrict__ pbuf, const float* __restrict__ wval,
        const int* __restrict__ eidx, const float* __restrict__ B2,
        float* __restrict__ out) {
    const int i = blockIdx.x * 256 + threadIdx.x;
    const int t = i >> 7, d = i & (NDIM - 1);
    const int KS = NPAIR * NDIM;
    float y[2];
#pragma unroll
    for (int k = 0; k < 2; ++k) {
        const int p = t * 2 + k;
        float s = pbuf[p * NDIM + d] + pbuf[KS + p * NDIM + d]
                + pbuf[2 * KS + p * NDIM + d] + pbuf[3 * KS + p * NDIM + d]
                + B2[eidx[p] * NDIM + d];
        y[k] = gelu_f(s);
    }
    out[i] = wval[t * 2] * y[0] + wval[t * 2 + 1] * y[1];
}

extern "C" void kernel_launch(void* const* d_in, const int* in_sizes, int n_in,
                              void* d_out, int out_size, void* d_ws, size_t ws_size,
                              hipStream_t stream) {
    const float* x   = (const float*)d_in[0];
    const float* gw1 = (const float*)d_in[1];
    const float* gb1 = (const float*)d_in[2];
    const float* gw2 = (const float*)d_in[3];
    const float* gb2 = (const float*)d_in[4];
    const float* gw3 = (const float*)d_in[5];
    const float* gb3 = (const float*)d_in[6];
    const float* W1  = (const float*)d_in[7];
    const float* B1  = (const float*)d_in[8];
    const float* W2  = (const float*)d_in[9];
    const float* B2  = (const float*)d_in[10];
    float* out = (float*)d_out;

    char* ws = (char*)d_ws;
    // h1 [0,2MB) | h2p [2,10MB) 4x2MB | tbuf(bf16) aliases [0,2MB) after gate3 |
    // pbuf [10,14MB) 4x1MB | control at 14MB+
    float*          h1   = (float*)(ws);
    float*          h2p  = (float*)(ws + (2ull << 20));
    unsigned short* tbuf = (unsigned short*)(ws);
    float*          pbuf = (float*)(ws + (10ull << 20));
    int*   eidx  = (int*)  (ws + (14ull << 20));
    float* wval  = (float*)(ws + (14ull << 20) + 8192);
    int*   elist = (int*)  (ws + (14ull << 20) + 16384);
    int*   ecnt  = (int*)  (ws + (14ull << 20) + 16384 + NEXPERT * NPAIR * 4);

    gemm64_kernel<<<dim3(16, 8, 1), 256, 0, stream>>>(x, gw1, gb1, h1, 128, NHID, 128, 1, 0);
    gemm64_kernel<<<dim3(16, 8, 4), 256, 0, stream>>>(h1, gw2, nullptr, h2p, NHID, NHID, 128, 0,
                                                      (long long)NTOK * NHID);
    gate3_top2_kernel<<<dim3(NTOK / 16), 256, 0, stream>>>(h2p, gb2, gw3, gb3, eidx, wval);
    build_lists_kernel<<<dim3(NEXPERT), 256, 0, stream>>>(eidx, elist, ecnt);
    expert_l1_kernel<<<dim3(NEXPERT, 8), 256, 0, stream>>>(x, W1, B1, elist, ecnt, tbuf);
    expert_l2_kernel<<<dim3(NEXPERT, 2, 4), 256, 0, stream>>>(W2, elist, ecnt, tbuf, pbuf);
    combine_kernel<<<dim3(NTOK * NDIM / 256), 256, 0, stream>>>(pbuf, wval, eidx, B2, out);
}